// Round 1
// baseline (852.241 us; speedup 1.0000x reference)
//
#include <hip/hip_runtime.h>
#include <math.h>

#define B_   32
#define H_   16
#define W_   256
#define M_   16384
#define EPS_ 1e-5f

// ws layout (in floats)
#define WS_KNORM 0                       // [512]
#define WS_SPP   512                     // [512]
#define WS_PMAX  1024                    // [512*256]
#define WS_PSUM  (1024 + 512*256)        // [512*256]
#define WS_GMAX  (1024 + 2*512*256)      // [512]
#define WS_GINV  (1024 + 2*512*256+512)  // [512]

// ---------------- kernel 0: key norms + softplus(strengths) ----------------
__global__ void __launch_bounds__(64)
prep_kernel(const float* __restrict__ keys, const float* __restrict__ strengths,
            float* __restrict__ ws) {
    const int bh   = blockIdx.x;     // 0..511
    const int lane = threadIdx.x;    // 0..63
    const float4 k4 = *(const float4*)(keys + (size_t)bh * W_ + lane * 4);
    float s = k4.x*k4.x + k4.y*k4.y + k4.z*k4.z + k4.w*k4.w;
    #pragma unroll
    for (int o = 32; o; o >>= 1) s += __shfl_xor(s, o);
    if (lane == 0) {
        ws[WS_KNORM + bh] = sqrtf(s + EPS_);
        float st = strengths[bh];
        ws[WS_SPP + bh] = (st > 20.f) ? st : log1pf(expf(st));
    }
}

// ---------------- kernel 1: dot + norms + sharp + softmax partials ----------
// grid: (M/256, B). block: 256 threads = 4 waves. wave owns 64 m rows.
#define WT_    32   // w-tile width (floats)
#define PITCH_ 36   // LDS row pitch in floats (144 B -> bank-quad (lane+c)%8)

__global__ void __launch_bounds__(256)
weight_main(const float* __restrict__ memory, const float* __restrict__ keys,
            float* __restrict__ out, float* __restrict__ ws) {
    __shared__ float keys_lds[H_ * W_];          // 16 KiB
    __shared__ float mem_lds[4 * 64 * PITCH_];   // 36 KiB

    const int b     = blockIdx.y;
    const int mtile = blockIdx.x;                // 0..63
    const int tid   = threadIdx.x;
    const int wave  = tid >> 6;
    const int lane  = tid & 63;

    // stage keys[b] (4096 floats) into LDS, coalesced float4
    {
        const float* kb = keys + (size_t)b * (H_ * W_);
        #pragma unroll
        for (int i = 0; i < 4; ++i) {
            int idx = tid + i * 256;             // float4 index
            *(float4*)&keys_lds[idx * 4] = *(const float4*)&kb[idx * 4];
        }
    }
    __syncthreads();

    const int m0 = mtile * 256 + wave * 64;      // wave's base m
    const int m  = m0 + lane;
    const float* mrow_base = memory + ((size_t)b * M_ + m0) * W_;
    float* myLds = mem_lds + wave * 64 * PITCH_; // wave-private region

    float acc[H_];
    #pragma unroll
    for (int h = 0; h < H_; ++h) acc[h] = 0.f;
    float sq = 0.f;

    const int r_st = lane >> 3;   // 0..7
    const int cb   = lane & 7;    // 0..7

    for (int wc = 0; wc < W_; wc += WT_) {
        // stage [64 rows x 32 w] tile: 8 coalesced float4 loads per lane
        float4 st[8];
        #pragma unroll
        for (int j = 0; j < 8; ++j) {
            int r = j * 8 + r_st;
            st[j] = *(const float4*)&mrow_base[(size_t)r * W_ + wc + cb * 4];
        }
        #pragma unroll
        for (int j = 0; j < 8; ++j) {
            int r = j * 8 + r_st;
            *(float4*)&myLds[r * PITCH_ + cb * 4] = st[j];
        }
        // wave-private tile: in-wave DS ordering suffices, no barrier.
        #pragma unroll
        for (int c = 0; c < 8; ++c) {
            float4 mf = *(float4*)&myLds[lane * PITCH_ + c * 4];
            sq += mf.x*mf.x + mf.y*mf.y + mf.z*mf.z + mf.w*mf.w;
            #pragma unroll
            for (int h = 0; h < H_; ++h) {
                float4 kf = *(float4*)&keys_lds[h * W_ + wc + c * 4]; // broadcast
                acc[h] += mf.x*kf.x + mf.y*kf.y + mf.z*kf.z + mf.w*kf.w;
            }
        }
    }

    // epilogue: sharp values + store + per-wave softmax partials
    const float mnorm = sqrtf(sq + EPS_);
    #pragma unroll
    for (int h = 0; h < H_; ++h) {
        float kn = ws[WS_KNORM + b * H_ + h];
        float sp = ws[WS_SPP   + b * H_ + h];
        float v  = acc[h] / (kn * mnorm + EPS_) * sp;
        acc[h] = v;
        out[((size_t)(b * H_ + h)) * M_ + m] = v;
    }
    const int chunk = mtile * 4 + wave;          // 0..255
    #pragma unroll
    for (int h = 0; h < H_; ++h) {
        float mx = acc[h];
        #pragma unroll
        for (int o = 32; o; o >>= 1) mx = fmaxf(mx, __shfl_xor(mx, o));
        float e = __expf(acc[h] - mx);
        #pragma unroll
        for (int o = 32; o; o >>= 1) e += __shfl_xor(e, o);
        if (lane == 0) {
            ws[WS_PMAX + (b * H_ + h) * 256 + chunk] = mx;
            ws[WS_PSUM + (b * H_ + h) * 256 + chunk] = e;
        }
    }
}

// ---------------- kernel 2: combine partials per (b,h) ----------------------
__global__ void __launch_bounds__(256)
reduce_kernel(float* __restrict__ ws) {
    __shared__ float wmax[4];
    __shared__ float wsum[4];
    const int bh   = blockIdx.x;
    const int tid  = threadIdx.x;
    const int lane = tid & 63;
    const int wave = tid >> 6;
    const float pm = ws[WS_PMAX + bh * 256 + tid];
    const float psv = ws[WS_PSUM + bh * 256 + tid];
    float mx = pm;
    #pragma unroll
    for (int o = 32; o; o >>= 1) mx = fmaxf(mx, __shfl_xor(mx, o));
    if (lane == 0) wmax[wave] = mx;
    __syncthreads();
    mx = fmaxf(fmaxf(wmax[0], wmax[1]), fmaxf(wmax[2], wmax[3]));
    float s = psv * __expf(pm - mx);
    #pragma unroll
    for (int o = 32; o; o >>= 1) s += __shfl_xor(s, o);
    if (lane == 0) wsum[wave] = s;
    __syncthreads();
    if (tid == 0) {
        float gs = wsum[0] + wsum[1] + wsum[2] + wsum[3];
        ws[WS_GMAX + bh] = mx;
        ws[WS_GINV + bh] = 1.f / gs;
    }
}

// ---------------- kernel 3: normalize in place ------------------------------
__global__ void __launch_bounds__(256)
norm_kernel(float* __restrict__ out, const float* __restrict__ ws) {
    const int bh  = blockIdx.x >> 4;              // 16 blocks per (b,h) row
    const int idx = blockIdx.x * 256 + threadIdx.x; // float4 index
    const float gm = ws[WS_GMAX + bh];
    const float gi = ws[WS_GINV + bh];
    float4 v = ((float4*)out)[idx];
    v.x = __expf(v.x - gm) * gi;
    v.y = __expf(v.y - gm) * gi;
    v.z = __expf(v.z - gm) * gi;
    v.w = __expf(v.w - gm) * gi;
    ((float4*)out)[idx] = v;
}

extern "C" void kernel_launch(void* const* d_in, const int* in_sizes, int n_in,
                              void* d_out, int out_size, void* d_ws, size_t ws_size,
                              hipStream_t stream) {
    const float* memory    = (const float*)d_in[0];
    const float* keys      = (const float*)d_in[1];
    const float* strengths = (const float*)d_in[2];
    float* out = (float*)d_out;
    float* ws  = (float*)d_ws;

    prep_kernel<<<dim3(B_ * H_), dim3(64), 0, stream>>>(keys, strengths, ws);
    weight_main<<<dim3(M_ / 256, B_), dim3(256), 0, stream>>>(memory, keys, out, ws);
    reduce_kernel<<<dim3(B_ * H_), dim3(256), 0, stream>>>(ws);
    norm_kernel<<<dim3((B_ * H_ * M_ / 4) / 256), dim3(256), 0, stream>>>(out, ws);
}

// Round 2
// 782.221 us; speedup vs baseline: 1.0895x; 1.0895x over previous
//
#include <hip/hip_runtime.h>
#include <math.h>

#define B_   32
#define H_   16
#define W_   256
#define M_   16384
#define EPS_ 1e-5f

// ws layout (in floats)
#define WS_KNORM 0                       // [512]
#define WS_SPP   512                     // [512]
#define WS_PMAX  1024                    // [512*256]
#define WS_PSUM  (1024 + 512*256)        // [512*256]
#define WS_GMAX  (1024 + 2*512*256)      // [512]
#define WS_GINV  (1024 + 2*512*256+512)  // [512]

// ---------------- kernel 0: key norms + softplus(strengths) ----------------
__global__ void __launch_bounds__(64)
prep_kernel(const float* __restrict__ keys, const float* __restrict__ strengths,
            float* __restrict__ ws) {
    const int bh   = blockIdx.x;     // 0..511
    const int lane = threadIdx.x;    // 0..63
    const float4 k4 = *(const float4*)(keys + (size_t)bh * W_ + lane * 4);
    float s = k4.x*k4.x + k4.y*k4.y + k4.z*k4.z + k4.w*k4.w;
    #pragma unroll
    for (int o = 32; o; o >>= 1) s += __shfl_xor(s, o);
    if (lane == 0) {
        ws[WS_KNORM + bh] = sqrtf(s + EPS_);
        float st = strengths[bh];
        ws[WS_SPP + bh] = (st > 20.f) ? st : log1pf(expf(st));
    }
}

// ---------------- kernel 1: dot + norms + sharp + softmax partials ----------
// grid: (M/256, B). block: 256 threads = 4 waves. wave owns 64 m rows.
// Keys are wave-uniform -> read via scalar loads (SGPRs), zero LDS traffic.
// Memory tile transposed through wave-private LDS (no barriers at all).
#define WT_    32   // w-tile width (floats)
#define PITCH_ 36   // LDS row pitch in floats: lane stride 4*36 -> banks 4l%32, conflict-free per 8-lane phase

__global__ void __launch_bounds__(256)
weight_main(const float* __restrict__ memory, const float* __restrict__ keys,
            float* __restrict__ out, float* __restrict__ ws) {
    __shared__ float mem_lds[4 * 64 * PITCH_];   // 36 KiB

    const int b     = blockIdx.y;
    const int mtile = blockIdx.x;                // 0..63
    const int tid   = threadIdx.x;
    const int wave  = tid >> 6;
    const int lane  = tid & 63;

    const int m0 = mtile * 256 + wave * 64;      // wave's base m
    const int m  = m0 + lane;
    const float* mrow_base = memory + ((size_t)b * M_ + m0) * W_;
    const float* kb = (const float*)__builtin_assume_aligned(keys + (size_t)b * (H_ * W_), 16);
    float* myLds = mem_lds + wave * 64 * PITCH_; // wave-private region

    float acc[H_];
    #pragma unroll
    for (int h = 0; h < H_; ++h) acc[h] = 0.f;
    float sq = 0.f;

    const int r_st = lane >> 3;   // 0..7
    const int cb   = lane & 7;    // 0..7

    for (int wc = 0; wc < W_; wc += WT_) {
        // stage [64 rows x 32 w] tile: 8 coalesced float4 loads per lane
        float4 st[8];
        #pragma unroll
        for (int j = 0; j < 8; ++j) {
            int r = j * 8 + r_st;
            st[j] = *(const float4*)&mrow_base[(size_t)r * W_ + wc + cb * 4];
        }
        #pragma unroll
        for (int j = 0; j < 8; ++j) {
            int r = j * 8 + r_st;
            *(float4*)&myLds[r * PITCH_ + cb * 4] = st[j];
        }
        // read back this lane's own 32 floats (wave-private tile: no barrier)
        float4 mf[8];
        #pragma unroll
        for (int c = 0; c < 8; ++c)
            mf[c] = *(float4*)&myLds[lane * PITCH_ + c * 4];

        #pragma unroll
        for (int c = 0; c < 8; ++c)
            sq += mf[c].x*mf[c].x + mf[c].y*mf[c].y + mf[c].z*mf[c].z + mf[c].w*mf[c].w;

        // keys: fully uniform indices -> s_load through constant cache
        #pragma unroll
        for (int h = 0; h < H_; ++h) {
            #pragma unroll
            for (int c = 0; c < 8; ++c) {
                const float4 kf = *(const float4*)&kb[h * W_ + wc + c * 4];
                acc[h] += mf[c].x*kf.x + mf[c].y*kf.y + mf[c].z*kf.z + mf[c].w*kf.w;
            }
        }
    }

    // epilogue: sharp values + store + per-wave softmax partials
    const float mnorm = sqrtf(sq + EPS_);
    #pragma unroll
    for (int h = 0; h < H_; ++h) {
        float kn = ws[WS_KNORM + b * H_ + h];
        float sp = ws[WS_SPP   + b * H_ + h];
        float v  = acc[h] / (kn * mnorm + EPS_) * sp;
        acc[h] = v;
        out[((size_t)(b * H_ + h)) * M_ + m] = v;
    }
    const int chunk = mtile * 4 + wave;          // 0..255
    #pragma unroll
    for (int h = 0; h < H_; ++h) {
        float mx = acc[h];
        #pragma unroll
        for (int o = 32; o; o >>= 1) mx = fmaxf(mx, __shfl_xor(mx, o));
        float e = __expf(acc[h] - mx);
        #pragma unroll
        for (int o = 32; o; o >>= 1) e += __shfl_xor(e, o);
        if (lane == 0) {
            ws[WS_PMAX + (b * H_ + h) * 256 + chunk] = mx;
            ws[WS_PSUM + (b * H_ + h) * 256 + chunk] = e;
        }
    }
}

// ---------------- kernel 2: combine partials per (b,h) ----------------------
__global__ void __launch_bounds__(256)
reduce_kernel(float* __restrict__ ws) {
    __shared__ float wmax[4];
    __shared__ float wsum[4];
    const int bh   = blockIdx.x;
    const int tid  = threadIdx.x;
    const int lane = tid & 63;
    const int wave = tid >> 6;
    const float pm = ws[WS_PMAX + bh * 256 + tid];
    const float psv = ws[WS_PSUM + bh * 256 + tid];
    float mx = pm;
    #pragma unroll
    for (int o = 32; o; o >>= 1) mx = fmaxf(mx, __shfl_xor(mx, o));
    if (lane == 0) wmax[wave] = mx;
    __syncthreads();
    mx = fmaxf(fmaxf(wmax[0], wmax[1]), fmaxf(wmax[2], wmax[3]));
    float s = psv * __expf(pm - mx);
    #pragma unroll
    for (int o = 32; o; o >>= 1) s += __shfl_xor(s, o);
    if (lane == 0) wsum[wave] = s;
    __syncthreads();
    if (tid == 0) {
        float gs = wsum[0] + wsum[1] + wsum[2] + wsum[3];
        ws[WS_GMAX + bh] = mx;
        ws[WS_GINV + bh] = 1.f / gs;
    }
}

// ---------------- kernel 3: normalize in place ------------------------------
__global__ void __launch_bounds__(256)
norm_kernel(float* __restrict__ out, const float* __restrict__ ws) {
    const int bh  = blockIdx.x >> 4;              // 16 blocks per (b,h) row
    const int idx = blockIdx.x * 256 + threadIdx.x; // float4 index
    const float gm = ws[WS_GMAX + bh];
    const float gi = ws[WS_GINV + bh];
    float4 v = ((float4*)out)[idx];
    v.x = __expf(v.x - gm) * gi;
    v.y = __expf(v.y - gm) * gi;
    v.z = __expf(v.z - gm) * gi;
    v.w = __expf(v.w - gm) * gi;
    ((float4*)out)[idx] = v;
}

extern "C" void kernel_launch(void* const* d_in, const int* in_sizes, int n_in,
                              void* d_out, int out_size, void* d_ws, size_t ws_size,
                              hipStream_t stream) {
    const float* memory    = (const float*)d_in[0];
    const float* keys      = (const float*)d_in[1];
    const float* strengths = (const float*)d_in[2];
    float* out = (float*)d_out;
    float* ws  = (float*)d_ws;

    prep_kernel<<<dim3(B_ * H_), dim3(64), 0, stream>>>(keys, strengths, ws);
    weight_main<<<dim3(M_ / 256, B_), dim3(256), 0, stream>>>(memory, keys, out, ws);
    reduce_kernel<<<dim3(B_ * H_), dim3(256), 0, stream>>>(ws);
    norm_kernel<<<dim3((B_ * H_ * M_ / 4) / 256), dim3(256), 0, stream>>>(out, ws);
}